// Round 1
// baseline (4918.904 us; speedup 1.0000x reference)
//
#include <hip/hip_runtime.h>

#define DI __device__ __forceinline__

static constexpr int NN = 20000;   // nodes
static constexpr int NE = 160000;  // edges
static constexpr int D  = 64;

DI float rl(float v, int lane) {
    return __int_as_float(__builtin_amdgcn_readlane(__float_as_int(v), lane));
}
DI float xr(float v, int m) { return __shfl_xor(v, m, 64); }
DI float wsum64(float v) {
    v += xr(v, 1); v += xr(v, 2); v += xr(v, 4);
    v += xr(v, 8); v += xr(v, 16); v += xr(v, 32);
    return v;
}
DI float hsum16(float v) {
    v += xr(v, 1); v += xr(v, 2); v += xr(v, 4); v += xr(v, 8);
    return v;
}

// ---------------- small prep kernels ----------------

__global__ void transpose_w(const float* __restrict__ mw, float* __restrict__ W2t) {
    int idx = blockIdx.x * 256 + threadIdx.x;      // 0..262143
    if (idx >= 64 * 64 * 64) return;
    int o = idx & 63, t = idx >> 6, d = t & 63, i = t >> 6;
    // W2t[(i*64+d)*64 + o] = memw_w[(o*64+i)*64 + d]
    W2t[idx] = mw[(o * 64 + i) * 64 + d];
}

// per-slot edge-independent constants:
// P[0..255]   q0[m][l]
// P[256..511] vc[m][l]
// P[512..575] vs[l]
// P[576..591] s0[m][h] (scaled by 0.25)
// P[592..607] s2[m][h] (scaled by 0.25)
__global__ void precomp_kernel(const float* __restrict__ cls_w, const float* __restrict__ sep,
                               const float* __restrict__ in_w, const float* __restrict__ in_b,
                               float* __restrict__ P) {
    int l = threadIdx.x;  // 64 threads
    float bq = in_b[l], bk = in_b[64 + l], bv = in_b[128 + l];
    float xs = sep[l];
    float ks = bk, vs = bv;
    for (int j = 0; j < 64; j++) {
        float xj = rl(xs, j);
        ks += in_w[(64 + l) * 64 + j] * xj;
        vs += in_w[(128 + l) * 64 + j] * xj;
    }
    P[512 + l] = vs;
    for (int m = 0; m < 4; m++) {
        float xc = cls_w[m * 64 + l];
        float q0 = bq, kc = bk, vc = bv;
        for (int j = 0; j < 64; j++) {
            float xj = rl(xc, j);
            q0 += in_w[l * 64 + j] * xj;
            kc += in_w[(64 + l) * 64 + j] * xj;
            vc += in_w[(128 + l) * 64 + j] * xj;
        }
        P[m * 64 + l] = q0;
        P[256 + m * 64 + l] = vc;
        float p0 = hsum16(q0 * kc);
        float p2 = hsum16(q0 * ks);
        if ((l & 15) == 0) {
            P[576 + m * 4 + (l >> 4)] = p0 * 0.25f;
            P[592 + m * 4 + (l >> 4)] = p2 * 0.25f;
        }
    }
}

__global__ void hist_kernel(const int* __restrict__ et, int* __restrict__ bc, int nE) {
    __shared__ int c[5];
    int t = threadIdx.x, b = blockIdx.x;
    if (t < 5) c[t] = 0;
    __syncthreads();
    int e = b * 256 + t;
    if (e < nE) atomicAdd(&c[et[e]], 1);
    __syncthreads();
    if (t < 5) bc[b * 5 + t] = c[t];
}

// cs[0..4] = counts per etype, cs[5..9] = exclusive start per etype
__global__ void scan_kernel(const int* __restrict__ bc, int* __restrict__ boff,
                            int* __restrict__ cs, int nb) {
    int t = threadIdx.x;
    if (t < 5) {
        int tot = 0;
        for (int b = 0; b < nb; b++) { boff[b * 5 + t] = tot; tot += bc[b * 5 + t]; }
        cs[t] = tot;
    }
    __syncthreads();
    if (t == 0) {
        int s = 0;
        for (int e = 0; e < 5; e++) { cs[5 + e] = s; s += cs[e]; }
    }
}

__global__ void rank_kernel(const int* __restrict__ et, const int* __restrict__ boff,
                            const int* __restrict__ cs, int* __restrict__ rowbase,
                            int* __restrict__ estride, int nE) {
    __shared__ int es[256];
    int t = threadIdx.x, b = blockIdx.x;
    int e = b * 256 + t;
    es[t] = (e < nE) ? et[e] : -1;
    __syncthreads();
    if (e < nE) {
        int my = es[t], intra = 0;
        for (int j = 0; j < t; j++) intra += (es[j] == my) ? 1 : 0;
        rowbase[e] = 4 * cs[5 + my] + boff[b * 5 + my] + intra;
        estride[e] = cs[my];
    }
}

__global__ void deg_kernel(const int* __restrict__ dst, float* __restrict__ deg, int nE) {
    int e = blockIdx.x * 256 + threadIdx.x;
    if (e < nE) atomicAdd(&deg[dst[e]], 1.0f);
}

// ---------------- encoder: one wave per item ----------------

template <bool NODE>
__global__ __launch_bounds__(512) void enc_kernel(
    const float* __restrict__ feat, const int* __restrict__ src, const int* __restrict__ dst,
    const float* __restrict__ cls_w,
    const float* __restrict__ in_w, const float* __restrict__ in_b,
    const float* __restrict__ out_w, const float* __restrict__ out_b,
    const float* __restrict__ ln1_g, const float* __restrict__ ln1_b,
    const float* __restrict__ ln2_g, const float* __restrict__ ln2_b,
    const float* __restrict__ ff1_w, const float* __restrict__ ff1_b,
    const float* __restrict__ ff2_w, const float* __restrict__ ff2_b,
    const float* __restrict__ mc_w, const float* __restrict__ mc_b,
    const float* __restrict__ P,
    const int* __restrict__ rowbase, const int* __restrict__ estride,
    float* __restrict__ mem_out, float* __restrict__ out_cat, float* __restrict__ out_label,
    int count) {
    __shared__ float KT[4096], VT[4096], OT[4096], F1T[1024], F2T[1024];
    int tid = threadIdx.x;
    for (int p = tid; p < 4096; p += 512) {
        int j = p >> 6, i = p & 63;
        KT[p] = in_w[(64 + i) * 64 + j];   // KT[j][i]
        VT[p] = in_w[(128 + i) * 64 + j];  // VT[j][i]
        OT[p] = out_w[i * 64 + j];         // OT[j][i]
    }
    for (int p = tid; p < 1024; p += 512) {
        int j = p >> 4, f = p & 15;        // F1T[j][f]
        F1T[p] = ff1_w[f * 64 + j];
        int f2 = p >> 6, i2 = p & 63;      // F2T[f2][i2]
        F2T[p] = ff2_w[i2 * 16 + f2];
    }
    __syncthreads();
    int w = tid >> 6, l = tid & 63;
    int item = blockIdx.x * 8 + w;
    if (item >= count) return;

    int ia = NODE ? item : src[item];
    float ha = feat[ia * 64 + l];
    float hb;
    if (NODE) hb = ha;
    else { int ib = dst[item]; hb = feat[ib * 64 + l]; }

    float bk = in_b[64 + l], bv = in_b[128 + l];
    float ka = bk, va = bv, kb = bk, vb = bv;
#pragma unroll 8
    for (int j = 0; j < 64; j++) {
        float xa = rl(ha, j);
        float kt = KT[j * 64 + l], vt = VT[j * 64 + l];
        ka += kt * xa;
        va += vt * xa;
        if (!NODE) {
            float xb = rl(hb, j);
            kb += kt * xb;
            vb += vt * xb;
        }
    }
    if (NODE) { kb = ka; vb = va; }

    int hd = l >> 4;
    float g1 = ln1_g[l], b1 = ln1_b[l], g2 = ln2_g[l], b2 = ln2_b[l];
    float f1b = ff1_b[l & 15], f2b = ff2_b[l], ob = out_b[l];
    float mem = 0.f;
    int rb = 0, st = 0;
    if (!NODE) { rb = rowbase[item]; st = estride[item]; }

    for (int m = 0; m < 4; m++) {
        float q0 = P[m * 64 + l];
        float vcm = P[256 + m * 64 + l];
        float vs = P[512 + l];
        float s0 = P[576 + m * 4 + hd];
        float s2 = P[592 + m * 4 + hd];
        float s1 = hsum16(q0 * ka) * 0.25f;
        float s3 = hsum16(q0 * kb) * 0.25f;
        float mx = fmaxf(fmaxf(s0, s1), fmaxf(s2, s3));
        float e0 = __expf(s0 - mx), e1 = __expf(s1 - mx), e2 = __expf(s2 - mx), e3 = __expf(s3 - mx);
        float inv = 1.f / (e0 + e1 + e2 + e3);
        float o0 = (e0 * vcm + e1 * va + e2 * vs + e3 * vb) * inv;

        float x = cls_w[m * 64 + l] + ob;
#pragma unroll 8
        for (int j = 0; j < 64; j++) x += OT[j * 64 + l] * rl(o0, j);
        // LN1
        float mu = wsum64(x) * (1.f / 64.f);
        float dx = x - mu;
        float var = wsum64(dx * dx) * (1.f / 64.f);
        float x1 = dx * rsqrtf(var + 1e-5f) * g1 + b1;
        // FF: 16 hidden, split across 4 quarters then xor-combine
        float hp = 0.f;
        {
            int f = l & 15, qd = l >> 4;
#pragma unroll
            for (int jj = 0; jj < 16; jj++) {
                int j = qd * 16 + jj;
                hp += F1T[j * 16 + f] * __shfl(x1, j, 64);
            }
            hp += xr(hp, 16);
            hp += xr(hp, 32);
        }
        float hr = fmaxf(hp + f1b, 0.f);   // lane l holds hidden unit (l&15)
        float y = x1 + f2b;
#pragma unroll
        for (int f2 = 0; f2 < 16; f2++) y += F2T[f2 * 64 + l] * rl(hr, f2);
        // LN2
        float mu2 = wsum64(y) * (1.f / 64.f);
        float dy = y - mu2;
        float v2 = wsum64(dy * dy) * (1.f / 64.f);
        float t = dy * rsqrtf(v2 + 1e-5f) * g2 + b2;
        mem += t;

        if (!NODE) {
            int row = rb + m * st;
            float cv = 0.f;
            for (int c = 0; c < 4; c++) {
                float pc = wsum64(mc_w[c * 64 + l] * t);
                if (l == c) cv = pc + mc_b[c];
            }
            if (l < 4) out_cat[(size_t)row * 4 + l] = cv;
            if (l == 0) out_label[row] = (float)m;
        }
    }
    mem_out[(size_t)item * 64 + l] = mem;
}

// ---------------- message bilinear: 8 items per wave ----------------

template <bool NODE>
__global__ __launch_bounds__(256) void msg_kernel(
    const float* __restrict__ feat, const int* __restrict__ src, const int* __restrict__ dstv,
    const float* __restrict__ memv, const float* __restrict__ W2t,
    float* __restrict__ outv, int count) {
    __shared__ float Wsh[8192];
    int tid = threadIdx.x, w = tid >> 6, l = tid & 63;
    int base_item = (blockIdx.x * 4 + w) * 8;
    float h[8], mm[8], acc[8];
#pragma unroll
    for (int it = 0; it < 8; it++) {
        int e = base_item + it;
        int ec = e < count ? e : count - 1;
        int hsrc = NODE ? ec : src[ec];
        h[it] = feat[(size_t)hsrc * 64 + l];
        mm[it] = memv[(size_t)ec * 64 + l];
        acc[it] = 0.f;
    }
    for (int i0 = 0; i0 < 64; i0 += 2) {
        __syncthreads();
        const float4* s4 = (const float4*)(W2t + i0 * 4096);
        float4* d4 = (float4*)Wsh;
#pragma unroll
        for (int r = 0; r < 8; r++) d4[r * 256 + tid] = s4[r * 256 + tid];
        __syncthreads();
#pragma unroll
        for (int ii = 0; ii < 2; ii++) {
            int i = i0 + ii;
            float u[8];
#pragma unroll
            for (int it = 0; it < 8; it++) u[it] = rl(h[it], i) * mm[it];
            const float* Wb = Wsh + ii * 4096;
#pragma unroll 4
            for (int d = 0; d < 64; d++) {
                float wv = Wb[d * 64 + l];
#pragma unroll
                for (int it = 0; it < 8; it++) acc[it] += rl(u[it], d) * wv;
            }
        }
    }
#pragma unroll
    for (int it = 0; it < 8; it++) {
        int e = base_item + it;
        if (e < count) {
            if (NODE) outv[(size_t)e * 64 + l] = acc[it];
            else atomicAdd(&outv[(size_t)dstv[e] * 64 + l], acc[it]);
        }
    }
}

// ---------------- final node combine ----------------

__global__ __launch_bounds__(256) void final_kernel(
    const float* __restrict__ agg, const float* __restrict__ deg, const float* __restrict__ msgn,
    const float* __restrict__ lnw_g, const float* __restrict__ lnw_b,
    const float* __restrict__ h_bias, float* __restrict__ outp, int nN) {
    int tid = threadIdx.x, w = tid >> 6, l = tid & 63;
    int n = blockIdx.x * 4 + w;
    if (n >= nN) return;
    float a = agg[(size_t)n * 64 + l] / fmaxf(deg[n], 1.f);
    float mu = wsum64(a) * (1.f / 64.f);
    float d = a - mu;
    float var = wsum64(d * d) * (1.f / 64.f);
    float v = d * rsqrtf(var + 1e-5f) * lnw_g[l] + lnw_b[l] + h_bias[l] + msgn[(size_t)n * 64 + l];
    outp[(size_t)n * 64 + l] = v > 0.f ? v : 0.2f * v;
}

// ---------------- host ----------------

extern "C" void kernel_launch(void* const* d_in, const int* in_sizes, int n_in,
                              void* d_out, int out_size, void* d_ws, size_t ws_size,
                              hipStream_t stream) {
    const float* feat   = (const float*)d_in[0];
    const int*   src    = (const int*)d_in[1];
    const int*   dst    = (const int*)d_in[2];
    const int*   etype  = (const int*)d_in[3];
    const float* cls_w  = (const float*)d_in[4];
    const float* sep    = (const float*)d_in[5];
    const float* in_w   = (const float*)d_in[6];
    const float* in_b   = (const float*)d_in[7];
    const float* out_w  = (const float*)d_in[8];
    const float* out_b  = (const float*)d_in[9];
    const float* ln1_g  = (const float*)d_in[10];
    const float* ln1_b  = (const float*)d_in[11];
    const float* ln2_g  = (const float*)d_in[12];
    const float* ln2_b  = (const float*)d_in[13];
    const float* ff1_w  = (const float*)d_in[14];
    const float* ff1_b  = (const float*)d_in[15];
    const float* ff2_w  = (const float*)d_in[16];
    const float* ff2_b  = (const float*)d_in[17];
    const float* mc_w   = (const float*)d_in[18];
    const float* mc_b   = (const float*)d_in[19];
    const float* memw_w = (const float*)d_in[20];
    const float* h_bias = (const float*)d_in[21];
    const float* lnw_g  = (const float*)d_in[22];
    const float* lnw_b  = (const float*)d_in[23];

    char* ws = (char*)d_ws;
    size_t off = 0;
    auto nxt = [&](size_t bytes) -> void* {
        void* p = ws + off;
        off += (bytes + 255) & ~(size_t)255;
        return p;
    };
    float* W2t     = (float*)nxt(64 * 64 * 64 * sizeof(float));  // 1 MB
    float* P       = (float*)nxt(1024 * sizeof(float));
    int*   bc      = (int*)nxt(625 * 5 * sizeof(int));
    int*   boff    = (int*)nxt(625 * 5 * sizeof(int));
    int*   cs      = (int*)nxt(16 * sizeof(int));
    int*   rowbase = (int*)nxt((size_t)NE * sizeof(int));
    int*   estride = (int*)nxt((size_t)NE * sizeof(int));
    float* mem_e   = (float*)nxt((size_t)NE * 64 * sizeof(float));
    float* mem_n   = (float*)nxt((size_t)NN * 64 * sizeof(float));
    float* agg     = (float*)nxt((size_t)NN * 64 * sizeof(float));
    float* deg     = (float*)nxt((size_t)NN * sizeof(float));
    float* msg_n   = (float*)nxt((size_t)NN * 64 * sizeof(float));
    (void)ws_size; (void)in_sizes; (void)n_in; (void)out_size;

    float* out_node  = (float*)d_out;
    float* out_cat   = out_node + (size_t)NN * 64;           // (4*E, 4)
    float* out_label = out_cat + (size_t)4 * NE * 4;         // (4*E,)

    hipMemsetAsync(agg, 0, (size_t)NN * 64 * sizeof(float), stream);
    hipMemsetAsync(deg, 0, (size_t)NN * sizeof(float), stream);

    transpose_w<<<(64 * 64 * 64) / 256, 256, 0, stream>>>(memw_w, W2t);
    precomp_kernel<<<1, 64, 0, stream>>>(cls_w, sep, in_w, in_b, P);

    int nb = (NE + 255) / 256;  // 625
    hist_kernel<<<nb, 256, 0, stream>>>(etype, bc, NE);
    scan_kernel<<<1, 64, 0, stream>>>(bc, boff, cs, nb);
    rank_kernel<<<nb, 256, 0, stream>>>(etype, boff, cs, rowbase, estride, NE);
    deg_kernel<<<nb, 256, 0, stream>>>(dst, deg, NE);

    enc_kernel<false><<<(NE + 7) / 8, 512, 0, stream>>>(
        feat, src, dst, cls_w, in_w, in_b, out_w, out_b, ln1_g, ln1_b, ln2_g, ln2_b,
        ff1_w, ff1_b, ff2_w, ff2_b, mc_w, mc_b, P, rowbase, estride,
        mem_e, out_cat, out_label, NE);
    enc_kernel<true><<<(NN + 7) / 8, 512, 0, stream>>>(
        feat, nullptr, nullptr, cls_w, in_w, in_b, out_w, out_b, ln1_g, ln1_b, ln2_g, ln2_b,
        ff1_w, ff1_b, ff2_w, ff2_b, mc_w, mc_b, P, nullptr, nullptr,
        mem_n, nullptr, nullptr, NN);

    msg_kernel<false><<<(NE + 31) / 32, 256, 0, stream>>>(feat, src, dst, mem_e, W2t, agg, NE);
    msg_kernel<true><<<(NN + 31) / 32, 256, 0, stream>>>(feat, nullptr, nullptr, mem_n, W2t, msg_n, NN);

    final_kernel<<<(NN + 3) / 4, 256, 0, stream>>>(agg, deg, msg_n, lnw_g, lnw_b, h_bias, out_node, NN);
}

// Round 2
// 1592.843 us; speedup vs baseline: 3.0881x; 3.0881x over previous
//
#include <hip/hip_runtime.h>

#define DI __device__ __forceinline__

static constexpr int NN = 20000;   // nodes
static constexpr int NE = 160000;  // edges

typedef __attribute__((ext_vector_type(8))) short bf16x8;
typedef __attribute__((ext_vector_type(4))) float f32x4;

DI float rl(float v, int lane) {
    return __int_as_float(__builtin_amdgcn_readlane(__float_as_int(v), lane));
}
DI float xr(float v, int m) { return __shfl_xor(v, m, 64); }
DI float wsum64(float v) {
    v += xr(v, 1); v += xr(v, 2); v += xr(v, 4);
    v += xr(v, 8); v += xr(v, 16); v += xr(v, 32);
    return v;
}
DI float hsum16(float v) {
    v += xr(v, 1); v += xr(v, 2); v += xr(v, 4); v += xr(v, 8);
    return v;
}
DI unsigned short f2bf(float x) {            // round-half-up bf16
    unsigned u = __float_as_uint(x) + 0x8000u;
    return (unsigned short)(u >> 16);
}
DI float bf2f(unsigned short s) { return __uint_as_float(((unsigned)s) << 16); }
DI unsigned pack_bf2(float x, float y) {     // [bf16(x) | bf16(y)<<16]
    unsigned ux = __float_as_uint(x) + 0x8000u;
    unsigned uy = __float_as_uint(y) + 0x8000u;
#if __has_builtin(__builtin_amdgcn_perm)
    return __builtin_amdgcn_perm(uy, ux, 0x07060302u);
#else
    return (ux >> 16) | (uy & 0xFFFF0000u);
#endif
}

// ---------------- prep: W -> bf16, layout [i][o][d] ----------------
// Wstg[(i*64+o)*64+d] = bf16(memw_w[(o*64+i)*64+d])
__global__ void prep_w(const float* __restrict__ mw, unsigned short* __restrict__ Wstg) {
    int idx = blockIdx.x * 256 + threadIdx.x;   // 262144 total
    int d = idx & 63, o = (idx >> 6) & 63, i = idx >> 12;
    Wstg[idx] = f2bf(mw[(o * 64 + i) * 64 + d]);
}

// per-slot edge-independent constants (same as R1)
__global__ void precomp_kernel(const float* __restrict__ cls_w, const float* __restrict__ sep,
                               const float* __restrict__ in_w, const float* __restrict__ in_b,
                               float* __restrict__ P) {
    int l = threadIdx.x;  // 64 threads
    float bq = in_b[l], bk = in_b[64 + l], bv = in_b[128 + l];
    float xs = sep[l];
    float ks = bk, vs = bv;
    for (int j = 0; j < 64; j++) {
        float xj = rl(xs, j);
        ks += in_w[(64 + l) * 64 + j] * xj;
        vs += in_w[(128 + l) * 64 + j] * xj;
    }
    P[512 + l] = vs;
    for (int m = 0; m < 4; m++) {
        float xc = cls_w[m * 64 + l];
        float q0 = bq, kc = bk, vc = bv;
        for (int j = 0; j < 64; j++) {
            float xj = rl(xc, j);
            q0 += in_w[l * 64 + j] * xj;
            kc += in_w[(64 + l) * 64 + j] * xj;
            vc += in_w[(128 + l) * 64 + j] * xj;
        }
        P[m * 64 + l] = q0;
        P[256 + m * 64 + l] = vc;
        float p0 = hsum16(q0 * kc);
        float p2 = hsum16(q0 * vs * 0.f + q0 * ks);  // hsum16(q0*ks)
        if ((l & 15) == 0) {
            P[576 + m * 4 + (l >> 4)] = p0 * 0.25f;
            P[592 + m * 4 + (l >> 4)] = p2 * 0.25f;
        }
    }
}

__global__ void hist_kernel(const int* __restrict__ et, int* __restrict__ bc, int nE) {
    __shared__ int c[5];
    int t = threadIdx.x, b = blockIdx.x;
    if (t < 5) c[t] = 0;
    __syncthreads();
    int e = b * 256 + t;
    if (e < nE) atomicAdd(&c[et[e]], 1);
    __syncthreads();
    if (t < 5) bc[b * 5 + t] = c[t];
}

__global__ void scan_kernel(const int* __restrict__ bc, int* __restrict__ boff,
                            int* __restrict__ cs, int nb) {
    int t = threadIdx.x;
    if (t < 5) {
        int tot = 0;
        for (int b = 0; b < nb; b++) { boff[b * 5 + t] = tot; tot += bc[b * 5 + t]; }
        cs[t] = tot;
    }
    __syncthreads();
    if (t == 0) {
        int s = 0;
        for (int e = 0; e < 5; e++) { cs[5 + e] = s; s += cs[e]; }
    }
}

// ballot-based stable rank (replaces O(256) serial loop)
__global__ void rank_kernel(const int* __restrict__ et, const int* __restrict__ boff,
                            const int* __restrict__ cs, int* __restrict__ rowbase,
                            int* __restrict__ estride, int nE) {
    __shared__ int wc[4][5];
    int tid = threadIdx.x, b = blockIdx.x;
    int w = tid >> 6, lane = tid & 63;
    int e = b * 256 + tid;
    bool valid = e < nE;
    int my = valid ? et[e] : 0;
    unsigned long long bal[5];
#pragma unroll
    for (int ty = 0; ty < 5; ty++) bal[ty] = __ballot(valid && my == ty);
    if (lane == 0) {
#pragma unroll
        for (int ty = 0; ty < 5; ty++) wc[w][ty] = __popcll(bal[ty]);
    }
    __syncthreads();
    if (valid) {
        unsigned long long lt = ((unsigned long long)1 << lane) - 1;
        int intra = __popcll(bal[my] & lt);
        int pre = 0;
        for (int w2 = 0; w2 < w; w2++) pre += wc[w2][my];
        rowbase[e] = 4 * cs[5 + my] + boff[b * 5 + my] + pre + intra;
        estride[e] = cs[my];
    }
}

__global__ void deg_kernel(const int* __restrict__ dst, float* __restrict__ deg, int nE) {
    int e = blockIdx.x * 256 + threadIdx.x;
    if (e < nE) atomicAdd(&deg[dst[e]], 1.0f);
}

// ---------------- encoder: one wave per item ----------------

template <bool NODE>
__global__ __launch_bounds__(512) void enc_kernel(
    const float* __restrict__ feat, const int* __restrict__ src, const int* __restrict__ dst,
    const float* __restrict__ cls_w,
    const float* __restrict__ in_w, const float* __restrict__ in_b,
    const float* __restrict__ out_w, const float* __restrict__ out_b,
    const float* __restrict__ ln1_g, const float* __restrict__ ln1_b,
    const float* __restrict__ ln2_g, const float* __restrict__ ln2_b,
    const float* __restrict__ ff1_w, const float* __restrict__ ff1_b,
    const float* __restrict__ ff2_w, const float* __restrict__ ff2_b,
    const float* __restrict__ mc_w, const float* __restrict__ mc_b,
    const float* __restrict__ P,
    const int* __restrict__ rowbase, const int* __restrict__ estride,
    float* __restrict__ mem_out, float* __restrict__ out_cat, float* __restrict__ out_label,
    int count) {
    // LDS: 32K (KV f32x2) + 16K (OT f32) + 2K + 2K (ff bf16) = 52KB -> 3 blocks/CU
    __shared__ float2 KV[4096];               // KV[j][l] = (K^T, V^T)
    __shared__ float OT[4096];                // OT[j][l]
    __shared__ unsigned short F1b[1024], F2b[1024];
    int tid = threadIdx.x;
    for (int p = tid; p < 4096; p += 512) {
        int j = p >> 6, i = p & 63;
        KV[p] = make_float2(in_w[(64 + i) * 64 + j], in_w[(128 + i) * 64 + j]);
        OT[p] = out_w[i * 64 + j];
    }
    for (int p = tid; p < 1024; p += 512) {
        int j = p >> 4, f = p & 15;
        F1b[p] = f2bf(ff1_w[f * 64 + j]);
        int f2 = p >> 6, i2 = p & 63;
        F2b[p] = f2bf(ff2_w[i2 * 16 + f2]);
    }
    __syncthreads();
    int w = tid >> 6, l = tid & 63;
    int item = blockIdx.x * 8 + w;
    if (item >= count) return;

    int ia = NODE ? item : src[item];
    float ha = feat[ia * 64 + l];
    float hb;
    if (NODE) hb = ha;
    else { int ib = dst[item]; hb = feat[ib * 64 + l]; }

    float bk = in_b[64 + l], bv = in_b[128 + l];
    float ka0 = 0.f, va0 = 0.f, ka1 = 0.f, va1 = 0.f;
    float kb0 = 0.f, vb0 = 0.f, kb1 = 0.f, vb1 = 0.f;
#pragma unroll 8
    for (int j = 0; j < 64; j += 2) {
        float2 kv0 = KV[j * 64 + l], kv1 = KV[(j + 1) * 64 + l];
        float xa0 = rl(ha, j), xa1 = rl(ha, j + 1);
        ka0 += kv0.x * xa0; va0 += kv0.y * xa0;
        ka1 += kv1.x * xa1; va1 += kv1.y * xa1;
        if (!NODE) {
            float xb0 = rl(hb, j), xb1 = rl(hb, j + 1);
            kb0 += kv0.x * xb0; vb0 += kv0.y * xb0;
            kb1 += kv1.x * xb1; vb1 += kv1.y * xb1;
        }
    }
    float ka = bk + ka0 + ka1, va = bv + va0 + va1;
    float kb, vb;
    if (NODE) { kb = ka; vb = va; }
    else { kb = bk + kb0 + kb1; vb = bv + vb0 + vb1; }

    int hd = l >> 4;
    float g1 = ln1_g[l], b1 = ln1_b[l], g2 = ln2_g[l], b2 = ln2_b[l];
    float f1b = ff1_b[l & 15], f2b = ff2_b[l], ob = out_b[l];
    float mem = 0.f;
    int rb = 0, st = 0;
    if (!NODE) { rb = rowbase[item]; st = estride[item]; }

    for (int m = 0; m < 4; m++) {
        float q0 = P[m * 64 + l];
        float vcm = P[256 + m * 64 + l];
        float vs = P[512 + l];
        float s0 = P[576 + m * 4 + hd];
        float s2 = P[592 + m * 4 + hd];
        float s1 = hsum16(q0 * ka) * 0.25f;
        float s3 = hsum16(q0 * kb) * 0.25f;
        float mx = fmaxf(fmaxf(s0, s1), fmaxf(s2, s3));
        float e0 = __expf(s0 - mx), e1 = __expf(s1 - mx), e2 = __expf(s2 - mx), e3 = __expf(s3 - mx);
        float inv = 1.f / (e0 + e1 + e2 + e3);
        float o0 = (e0 * vcm + e1 * va + e2 * vs + e3 * vb) * inv;

        // out-proj: 4 independent FMA chains (was 1 -> latency-bound)
        float x0 = 0.f, x1a = 0.f, x2 = 0.f, x3 = 0.f;
#pragma unroll 8
        for (int j = 0; j < 64; j += 4) {
            x0  += OT[(j + 0) * 64 + l] * rl(o0, j + 0);
            x1a += OT[(j + 1) * 64 + l] * rl(o0, j + 1);
            x2  += OT[(j + 2) * 64 + l] * rl(o0, j + 2);
            x3  += OT[(j + 3) * 64 + l] * rl(o0, j + 3);
        }
        float x = cls_w[m * 64 + l] + ob + ((x0 + x1a) + (x2 + x3));
        // LN1
        float mu = wsum64(x) * (1.f / 64.f);
        float dx = x - mu;
        float var = wsum64(dx * dx) * (1.f / 64.f);
        float x1 = dx * rsqrtf(var + 1e-5f) * g1 + b1;
        // FF: 16 hidden, quarters + xor-combine, 2 chains
        float hp;
        {
            int f = l & 15, qd = l >> 4;
            float hp0 = 0.f, hp1 = 0.f;
#pragma unroll
            for (int jj = 0; jj < 16; jj += 2) {
                int j = qd * 16 + jj;
                hp0 += bf2f(F1b[j * 16 + f]) * __shfl(x1, j, 64);
                hp1 += bf2f(F1b[(j + 1) * 16 + f]) * __shfl(x1, j + 1, 64);
            }
            hp = hp0 + hp1;
            hp += xr(hp, 16);
            hp += xr(hp, 32);
        }
        float hr = fmaxf(hp + f1b, 0.f);   // lane l holds hidden unit (l&15)
        float y0 = 0.f, y1 = 0.f;
#pragma unroll
        for (int f2i = 0; f2i < 16; f2i += 2) {
            y0 += bf2f(F2b[(f2i + 0) * 64 + l]) * rl(hr, f2i + 0);
            y1 += bf2f(F2b[(f2i + 1) * 64 + l]) * rl(hr, f2i + 1);
        }
        float y = x1 + f2b + y0 + y1;
        // LN2
        float mu2 = wsum64(y) * (1.f / 64.f);
        float dy = y - mu2;
        float v2 = wsum64(dy * dy) * (1.f / 64.f);
        float t = dy * rsqrtf(v2 + 1e-5f) * g2 + b2;
        mem += t;

        if (!NODE) {
            int row = rb + m * st;
            float cv = 0.f;
            for (int c = 0; c < 4; c++) {
                float pc = wsum64(mc_w[c * 64 + l] * t);
                if (l == c) cv = pc + mc_b[c];
            }
            if (l < 4) out_cat[(size_t)row * 4 + l] = cv;
            if (l == 0) out_label[row] = (float)m;
        }
    }
    mem_out[(size_t)item * 64 + l] = mem;
}

// ---------------- message bilinear via MFMA ----------------
// msg[e,o] = sum_{i,d} (h[e,i]*mem[e,d]) * W[(i,d),o]
// Tall GEMM U(180k x 4096) @ W(4096 x 64); A-frags built on the fly (never
// materialized). Block = 4 waves x 64 items = 256 items; wave tile = 64x64.

template <bool NODE>
__global__ __launch_bounds__(256, 2) void msg_mfma(
    const float* __restrict__ feat, const int* __restrict__ src, const int* __restrict__ dstv,
    const float* __restrict__ memv, const unsigned short* __restrict__ Wstg,
    float* __restrict__ outv, int count) {
    constexpr int RS = 72;  // padded LDS row stride (bf16 elems): 144B, 16B-aligned, bank-balanced
    __shared__ __align__(16) unsigned short Wt[4 * 64 * RS];  // 36864 B
    __shared__ float hT[4 * 256];                             // 4096 B
    int tid = threadIdx.x;
    int w = tid >> 6, lane = tid & 63;
    int m16 = lane & 15, q = lane >> 4;
    int blockbase = blockIdx.x * 256;
    int wavebase = w * 64;

    // preload this wave's mem rows in A-fragment order (f32, reused for all i)
    float memf[4][2][8];
#pragma unroll
    for (int Mt = 0; Mt < 4; Mt++) {
        int it = blockbase + wavebase + Mt * 16 + m16;
        if (it >= count) it = count - 1;
        const float* mrow = memv + (size_t)it * 64;
#pragma unroll
        for (int ks = 0; ks < 2; ks++) {
            float4 a = *(const float4*)(mrow + ks * 32 + q * 8);
            float4 b = *(const float4*)(mrow + ks * 32 + q * 8 + 4);
            memf[Mt][ks][0] = a.x; memf[Mt][ks][1] = a.y;
            memf[Mt][ks][2] = a.z; memf[Mt][ks][3] = a.w;
            memf[Mt][ks][4] = b.x; memf[Mt][ks][5] = b.y;
            memf[Mt][ks][6] = b.z; memf[Mt][ks][7] = b.w;
        }
    }
    f32x4 acc[4][4];
#pragma unroll
    for (int Mt = 0; Mt < 4; Mt++)
#pragma unroll
        for (int nt = 0; nt < 4; nt++) {
            f32x4 z = {0.f, 0.f, 0.f, 0.f};
            acc[Mt][nt] = z;
        }

    for (int ch = 0; ch < 16; ch++) {   // 16 chunks x 4 i = K over i
        __syncthreads();
        // stage W chunk: 4 i x 64 o x 64 d bf16 (32KB), padded rows
        const unsigned short* gsl = Wstg + (size_t)ch * 4 * 4096;
#pragma unroll
        for (int p = 0; p < 8; p++) {
            int flat = p * 2048 + tid * 8;
            int ic = flat >> 12, o = (flat >> 6) & 63, d = flat & 63;
            uint4 v = *(const uint4*)(gsl + flat);
            *(uint4*)&Wt[(ic * 64 + o) * RS + d] = v;
        }
        // stage h chunk: hT[il][item_in_block]
        {
            int it = blockbase + tid;
            if (it >= count) it = count - 1;
            int hidx = NODE ? it : src[it];
            float4 hv = *(const float4*)(feat + (size_t)hidx * 64 + ch * 4);
            hT[0 * 256 + tid] = hv.x;
            hT[1 * 256 + tid] = hv.y;
            hT[2 * 256 + tid] = hv.z;
            hT[3 * 256 + tid] = hv.w;
        }
        __syncthreads();

#pragma unroll
        for (int il = 0; il < 4; il++) {
            float hM[4];
#pragma unroll
            for (int Mt = 0; Mt < 4; Mt++)
                hM[Mt] = hT[il * 256 + wavebase + Mt * 16 + m16];
            // build A-frags: bf16(h * mem)
            bf16x8 afr[4][2];
#pragma unroll
            for (int Mt = 0; Mt < 4; Mt++)
#pragma unroll
                for (int ks = 0; ks < 2; ks++) {
                    union { unsigned u[4]; bf16x8 v; } uu;
#pragma unroll
                    for (int jj = 0; jj < 4; jj++) {
                        float p0 = memf[Mt][ks][jj * 2 + 0] * hM[Mt];
                        float p1 = memf[Mt][ks][jj * 2 + 1] * hM[Mt];
                        uu.u[jj] = pack_bf2(p0, p1);
                    }
                    afr[Mt][ks] = uu.v;
                }
            const unsigned short* wrow = &Wt[(il * 64) * RS];
#pragma unroll
            for (int nt = 0; nt < 4; nt++) {
#pragma unroll
                for (int ks = 0; ks < 2; ks++) {
                    int o = nt * 16 + m16;
                    union { uint4 u; bf16x8 v; } bb;
                    bb.u = *(const uint4*)&wrow[o * RS + ks * 32 + q * 8];
#pragma unroll
                    for (int Mt = 0; Mt < 4; Mt++)
                        acc[Mt][nt] = __builtin_amdgcn_mfma_f32_16x16x32_bf16(
                            afr[Mt][ks], bb.v, acc[Mt][nt], 0, 0, 0);
                }
            }
        }
    }
    // writeout: lane holds D[row=q*4+r][col=m16] per (Mt,nt)
#pragma unroll
    for (int Mt = 0; Mt < 4; Mt++) {
        int ib = blockbase + wavebase + Mt * 16 + q * 4;
        if (NODE) {
#pragma unroll
            for (int r = 0; r < 4; r++) {
                int it = ib + r;
                if (it < count) {
#pragma unroll
                    for (int nt = 0; nt < 4; nt++)
                        outv[(size_t)it * 64 + nt * 16 + m16] = acc[Mt][nt][r];
                }
            }
        } else {
            int4 dd = *(const int4*)(dstv + ib);
#pragma unroll
            for (int r = 0; r < 4; r++) {
                int it = ib + r;
                if (it < count) {
                    int dn = (&dd.x)[r];
#pragma unroll
                    for (int nt = 0; nt < 4; nt++)
                        atomicAdd(&outv[(size_t)dn * 64 + nt * 16 + m16], acc[Mt][nt][r]);
                }
            }
        }
    }
}

// ---------------- final node combine ----------------

__global__ __launch_bounds__(256) void final_kernel(
    const float* __restrict__ agg, const float* __restrict__ deg, const float* __restrict__ msgn,
    const float* __restrict__ lnw_g, const float* __restrict__ lnw_b,
    const float* __restrict__ h_bias, float* __restrict__ outp, int nN) {
    int tid = threadIdx.x, w = tid >> 6, l = tid & 63;
    int n = blockIdx.x * 4 + w;
    if (n >= nN) return;
    float a = agg[(size_t)n * 64 + l] / fmaxf(deg[n], 1.f);
    float mu = wsum64(a) * (1.f / 64.f);
    float d = a - mu;
    float var = wsum64(d * d) * (1.f / 64.f);
    float v = d * rsqrtf(var + 1e-5f) * lnw_g[l] + lnw_b[l] + h_bias[l] + msgn[(size_t)n * 64 + l];
    outp[(size_t)n * 64 + l] = v > 0.f ? v : 0.2f * v;
}

// ---------------- host ----------------

extern "C" void kernel_launch(void* const* d_in, const int* in_sizes, int n_in,
                              void* d_out, int out_size, void* d_ws, size_t ws_size,
                              hipStream_t stream) {
    const float* feat   = (const float*)d_in[0];
    const int*   src    = (const int*)d_in[1];
    const int*   dst    = (const int*)d_in[2];
    const int*   etype  = (const int*)d_in[3];
    const float* cls_w  = (const float*)d_in[4];
    const float* sep    = (const float*)d_in[5];
    const float* in_w   = (const float*)d_in[6];
    const float* in_b   = (const float*)d_in[7];
    const float* out_w  = (const float*)d_in[8];
    const float* out_b  = (const float*)d_in[9];
    const float* ln1_g  = (const float*)d_in[10];
    const float* ln1_b  = (const float*)d_in[11];
    const float* ln2_g  = (const float*)d_in[12];
    const float* ln2_b  = (const float*)d_in[13];
    const float* ff1_w  = (const float*)d_in[14];
    const float* ff1_b  = (const float*)d_in[15];
    const float* ff2_w  = (const float*)d_in[16];
    const float* ff2_b  = (const float*)d_in[17];
    const float* mc_w   = (const float*)d_in[18];
    const float* mc_b   = (const float*)d_in[19];
    const float* memw_w = (const float*)d_in[20];
    const float* h_bias = (const float*)d_in[21];
    const float* lnw_g  = (const float*)d_in[22];
    const float* lnw_b  = (const float*)d_in[23];

    char* ws = (char*)d_ws;
    size_t off = 0;
    auto nxt = [&](size_t bytes) -> void* {
        void* p = ws + off;
        off += (bytes + 255) & ~(size_t)255;
        return p;
    };
    unsigned short* Wstg = (unsigned short*)nxt(64 * 64 * 64 * sizeof(unsigned short));  // 512 KB
    float* P       = (float*)nxt(1024 * sizeof(float));
    int*   bc      = (int*)nxt(625 * 5 * sizeof(int));
    int*   boff    = (int*)nxt(625 * 5 * sizeof(int));
    int*   cs      = (int*)nxt(16 * sizeof(int));
    int*   rowbase = (int*)nxt((size_t)NE * sizeof(int));
    int*   estride = (int*)nxt((size_t)NE * sizeof(int));
    float* mem_e   = (float*)nxt((size_t)NE * 64 * sizeof(float));
    float* mem_n   = (float*)nxt((size_t)NN * 64 * sizeof(float));
    float* agg     = (float*)nxt((size_t)NN * 64 * sizeof(float));
    float* deg     = (float*)nxt((size_t)NN * sizeof(float));
    float* msg_n   = (float*)nxt((size_t)NN * 64 * sizeof(float));
    (void)ws_size; (void)in_sizes; (void)n_in; (void)out_size;

    float* out_node  = (float*)d_out;
    float* out_cat   = out_node + (size_t)NN * 64;           // (4*E, 4)
    float* out_label = out_cat + (size_t)4 * NE * 4;         // (4*E,)

    hipMemsetAsync(agg, 0, (size_t)NN * 64 * sizeof(float), stream);
    hipMemsetAsync(deg, 0, (size_t)NN * sizeof(float), stream);

    prep_w<<<1024, 256, 0, stream>>>(memw_w, Wstg);
    precomp_kernel<<<1, 64, 0, stream>>>(cls_w, sep, in_w, in_b, P);

    int nb = (NE + 255) / 256;  // 625
    hist_kernel<<<nb, 256, 0, stream>>>(etype, bc, NE);
    scan_kernel<<<1, 64, 0, stream>>>(bc, boff, cs, nb);
    rank_kernel<<<nb, 256, 0, stream>>>(etype, boff, cs, rowbase, estride, NE);
    deg_kernel<<<nb, 256, 0, stream>>>(dst, deg, NE);

    enc_kernel<false><<<(NE + 7) / 8, 512, 0, stream>>>(
        feat, src, dst, cls_w, in_w, in_b, out_w, out_b, ln1_g, ln1_b, ln2_g, ln2_b,
        ff1_w, ff1_b, ff2_w, ff2_b, mc_w, mc_b, P, rowbase, estride,
        mem_e, out_cat, out_label, NE);
    enc_kernel<true><<<(NN + 7) / 8, 512, 0, stream>>>(
        feat, nullptr, nullptr, cls_w, in_w, in_b, out_w, out_b, ln1_g, ln1_b, ln2_g, ln2_b,
        ff1_w, ff1_b, ff2_w, ff2_b, mc_w, mc_b, P, nullptr, nullptr,
        mem_n, nullptr, nullptr, NN);

    msg_mfma<false><<<(NE + 255) / 256, 256, 0, stream>>>(feat, src, dst, mem_e, Wstg, agg, NE);
    msg_mfma<true><<<(NN + 255) / 256, 256, 0, stream>>>(feat, nullptr, nullptr, mem_n, Wstg, msg_n, NN);

    final_kernel<<<(NN + 3) / 4, 256, 0, stream>>>(agg, deg, msg_n, lnw_g, lnw_b, h_bias, out_node, NN);
}

// Round 3
// 956.198 us; speedup vs baseline: 5.1442x; 1.6658x over previous
//
#include <hip/hip_runtime.h>

#define DI __device__ __forceinline__

static constexpr int NN = 20000;   // nodes
static constexpr int NE = 160000;  // edges

typedef __attribute__((ext_vector_type(8))) short bf16x8;
typedef __attribute__((ext_vector_type(4))) float f32x4;

DI float rl(float v, int lane) {
    return __int_as_float(__builtin_amdgcn_readlane(__float_as_int(v), lane));
}
DI float xr(float v, int m) { return __shfl_xor(v, m, 64); }
DI float wsum64(float v) {
    v += xr(v, 1); v += xr(v, 2); v += xr(v, 4);
    v += xr(v, 8); v += xr(v, 16); v += xr(v, 32);
    return v;
}
DI float hsum16(float v) {
    v += xr(v, 1); v += xr(v, 2); v += xr(v, 4); v += xr(v, 8);
    return v;
}
// DPP-based reductions: pure VALU, no LDS-pipe traffic.
DI float hsum16d(float v) {
    v += __int_as_float(__builtin_amdgcn_mov_dpp(__float_as_int(v), 0xB1, 0xF, 0xF, true));   // xor1
    v += __int_as_float(__builtin_amdgcn_mov_dpp(__float_as_int(v), 0x4E, 0xF, 0xF, true));   // xor2
    v += __int_as_float(__builtin_amdgcn_mov_dpp(__float_as_int(v), 0x141, 0xF, 0xF, true));  // half mirror
    v += __int_as_float(__builtin_amdgcn_mov_dpp(__float_as_int(v), 0x140, 0xF, 0xF, true));  // row mirror
    return v;
}
DI float wsum64v(float v) {
    v = hsum16d(v);
    return (rl(v, 0) + rl(v, 16)) + (rl(v, 32) + rl(v, 48));
}
DI unsigned short f2bf(float x) {
    unsigned u = __float_as_uint(x) + 0x8000u;
    return (unsigned short)(u >> 16);
}
DI unsigned pack_bf2(float x, float y) {
    unsigned ux = __float_as_uint(x) + 0x8000u;
    unsigned uy = __float_as_uint(y) + 0x8000u;
#if __has_builtin(__builtin_amdgcn_perm)
    return __builtin_amdgcn_perm(uy, ux, 0x07060302u);
#else
    return (ux >> 16) | (uy & 0xFFFF0000u);
#endif
}

// ---------------- prep: W -> bf16, layout [i][o][d] (for msg MFMA) ----------------
__global__ void prep_w(const float* __restrict__ mw, unsigned short* __restrict__ Wstg) {
    int idx = blockIdx.x * 256 + threadIdx.x;   // 262144 total
    int d = idx & 63, o = (idx >> 6) & 63, i = idx >> 12;
    Wstg[idx] = f2bf(mw[(o * 64 + i) * 64 + d]);
}

// per-slot edge-independent constants:
// P[0..255] q0[m][l] | P[256..511] vc[m][l] | P[512..575] vs[l]
// P[576..591] s0[m][h]*0.25 | P[592..607] s2[m][h]*0.25
__global__ void precomp_kernel(const float* __restrict__ cls_w, const float* __restrict__ sep,
                               const float* __restrict__ in_w, const float* __restrict__ in_b,
                               float* __restrict__ P) {
    int l = threadIdx.x;  // 64 threads
    float bq = in_b[l], bk = in_b[64 + l], bv = in_b[128 + l];
    float xs = sep[l];
    float ks = bk, vs = bv;
    for (int j = 0; j < 64; j++) {
        float xj = rl(xs, j);
        ks += in_w[(64 + l) * 64 + j] * xj;
        vs += in_w[(128 + l) * 64 + j] * xj;
    }
    P[512 + l] = vs;
    for (int m = 0; m < 4; m++) {
        float xc = cls_w[m * 64 + l];
        float q0 = bq, kc = bk, vc = bv;
        for (int j = 0; j < 64; j++) {
            float xj = rl(xc, j);
            q0 += in_w[l * 64 + j] * xj;
            kc += in_w[(64 + l) * 64 + j] * xj;
            vc += in_w[(128 + l) * 64 + j] * xj;
        }
        P[m * 64 + l] = q0;
        P[256 + m * 64 + l] = vc;
        float p0 = hsum16(q0 * kc);
        float p2 = hsum16(q0 * ks);
        if ((l & 15) == 0) {
            P[576 + m * 4 + (l >> 4)] = p0 * 0.25f;
            P[592 + m * 4 + (l >> 4)] = p2 * 0.25f;
        }
    }
}

// fused small matrices derived from P + weights (single block, 256 thr)
// SWg[(m*4+h)*64+j] = 0.25*sum_i q0_m[h16+i]*Wk[h16+i][j]
// SB16[m*4+h]       = 0.25*sum_i q0_m[h16+i]*bk[h16+i]
// OvcG[(m*64+l)*4+h]= sum_i out_w[l][h16+i]*vc_m[h16+i]
// OvsG[l*4+h]       = sum_i out_w[l][h16+i]*vs[h16+i]
// bOvG[l*4+h]       = sum_i out_w[l][h16+i]*bv[h16+i]
// s0x[h*4+m]=P[576+m*4+h], s2x likewise; MC8[0..3]=Mc, [4..7]=Cc
__global__ void prep2_kernel(const float* __restrict__ in_w, const float* __restrict__ in_b,
                             const float* __restrict__ out_w,
                             const float* __restrict__ mc_w, const float* __restrict__ mc_b,
                             const float* __restrict__ ln2_g, const float* __restrict__ ln2_b,
                             const float* __restrict__ P,
                             float* __restrict__ SWg, float* __restrict__ SB16,
                             float* __restrict__ OvcG, float* __restrict__ OvsG,
                             float* __restrict__ bOvG, float* __restrict__ s0x,
                             float* __restrict__ s2x, float* __restrict__ MC8) {
    int t = threadIdx.x;
    for (int u = t; u < 1024; u += 256) {       // SW
        int m = u >> 8, h = (u >> 6) & 3, j = u & 63;
        float acc = 0.f;
        for (int i = 0; i < 16; i++)
            acc += P[m * 64 + h * 16 + i] * in_w[(64 + h * 16 + i) * 64 + j];
        SWg[u] = 0.25f * acc;
    }
    for (int u = t; u < 1024; u += 256) {       // Ovc
        int h = u & 3, l = (u >> 2) & 63, m = u >> 8;
        float acc = 0.f;
        for (int i = 0; i < 16; i++)
            acc += out_w[l * 64 + h * 16 + i] * P[256 + m * 64 + h * 16 + i];
        OvcG[u] = acc;
    }
    if (t < 256) {                              // Ovs, bOv
        int h = t & 3, l = t >> 2;
        float a1 = 0.f, a2 = 0.f;
        for (int i = 0; i < 16; i++) {
            a1 += out_w[l * 64 + h * 16 + i] * P[512 + h * 16 + i];
            a2 += out_w[l * 64 + h * 16 + i] * in_b[128 + h * 16 + i];
        }
        OvsG[t] = a1;
        bOvG[t] = a2;
    }
    if (t < 16) {                               // SB16, s0x, s2x
        int m = t >> 2, h = t & 3;
        float acc = 0.f;
        for (int i = 0; i < 16; i++)
            acc += P[m * 64 + h * 16 + i] * in_b[64 + h * 16 + i];
        SB16[t] = 0.25f * acc;
        int h2 = t >> 2, m2 = t & 3;
        s0x[t] = P[576 + m2 * 4 + h2];
        s2x[t] = P[592 + m2 * 4 + h2];
    }
    if (t < 8) {                                // Mc / Cc
        int c = t & 3;
        float acc = 0.f;
        if (t < 4) {
            for (int l = 0; l < 64; l++) acc += mc_w[c * 64 + l] * ln2_g[l];
        } else {
            for (int l = 0; l < 64; l++) acc += mc_w[c * 64 + l] * ln2_b[l];
            acc += mc_b[c];
        }
        MC8[t] = acc;
    }
}

// WOVg[(j*64+l)*4+h] = sum_i out_w[l][h16+i]*Wv[h16+i][j]
__global__ void prep_wov(const float* __restrict__ in_w, const float* __restrict__ out_w,
                         float* __restrict__ WOVg) {
    int u = blockIdx.x * 256 + threadIdx.x;     // 16384
    int h = u & 3, l = (u >> 2) & 63, j = u >> 8;
    float acc = 0.f;
    for (int i = 0; i < 16; i++)
        acc += out_w[l * 64 + h * 16 + i] * in_w[(128 + h * 16 + i) * 64 + j];
    WOVg[u] = acc;
}

// ---------------- per-node stage: S[n][h*4+m], Ov[n][l][h] ----------------
__global__ __launch_bounds__(256) void node_pre(
    const float* __restrict__ feat, const float* __restrict__ SWg,
    const float* __restrict__ SB16, const float* __restrict__ WOVg,
    const float* __restrict__ bOvG, float* __restrict__ Sout, float* __restrict__ Ovout) {
    __shared__ float SWs[1024];
    __shared__ f32x4 WOVs[4096];
    int tid = threadIdx.x;
    for (int p = tid; p < 1024; p += 256) SWs[p] = SWg[p];
    for (int p = tid; p < 4096; p += 256) WOVs[p] = ((const f32x4*)WOVg)[p];
    __syncthreads();
    int w = tid >> 6, l = tid & 63;
    int n = blockIdx.x * 4 + w;
    float f = feat[(size_t)n * 64 + l];
#pragma unroll
    for (int mh = 0; mh < 16; mh++) {
        float v = SWs[mh * 64 + l] * f;
        v = wsum64v(v);
        if (l == mh) Sout[(size_t)n * 16 + (mh & 3) * 4 + (mh >> 2)] = v + SB16[mh];
    }
    f32x4 acc = ((const f32x4*)bOvG)[l];
#pragma unroll 8
    for (int j = 0; j < 64; j++) {
        float fj = rl(f, j);
        f32x4 wv = WOVs[j * 64 + l];
        acc += wv * fj;
    }
    ((f32x4*)Ovout)[(size_t)n * 64 + l] = acc;
}

// ---------------- edge-order bookkeeping ----------------

__global__ void hist_kernel(const int* __restrict__ et, int* __restrict__ bc, int nE) {
    __shared__ int c[5];
    int t = threadIdx.x, b = blockIdx.x;
    if (t < 5) c[t] = 0;
    __syncthreads();
    int e = b * 256 + t;
    if (e < nE) atomicAdd(&c[et[e]], 1);
    __syncthreads();
    if (t < 5) bc[b * 5 + t] = c[t];
}

__global__ void scan_kernel(const int* __restrict__ bc, int* __restrict__ boff,
                            int* __restrict__ cs, int nb) {
    int t = threadIdx.x;
    if (t < 5) {
        int tot = 0;
        for (int b = 0; b < nb; b++) { boff[b * 5 + t] = tot; tot += bc[b * 5 + t]; }
        cs[t] = tot;
    }
    __syncthreads();
    if (t == 0) {
        int s = 0;
        for (int e = 0; e < 5; e++) { cs[5 + e] = s; s += cs[e]; }
    }
}

__global__ void rank_kernel(const int* __restrict__ et, const int* __restrict__ boff,
                            const int* __restrict__ cs, int* __restrict__ rowbase,
                            int* __restrict__ estride, int nE) {
    __shared__ int wc[4][5];
    int tid = threadIdx.x, b = blockIdx.x;
    int w = tid >> 6, lane = tid & 63;
    int e = b * 256 + tid;
    bool valid = e < nE;
    int my = valid ? et[e] : 0;
    unsigned long long bal[5];
#pragma unroll
    for (int ty = 0; ty < 5; ty++) bal[ty] = __ballot(valid && my == ty);
    if (lane == 0) {
#pragma unroll
        for (int ty = 0; ty < 5; ty++) wc[w][ty] = __popcll(bal[ty]);
    }
    __syncthreads();
    if (valid) {
        unsigned long long lt = ((unsigned long long)1 << lane) - 1;
        int intra = __popcll(bal[my] & lt);
        int pre = 0;
        for (int w2 = 0; w2 < w; w2++) pre += wc[w2][my];
        rowbase[e] = 4 * cs[5 + my] + boff[b * 5 + my] + pre + intra;
        estride[e] = cs[my];
    }
}

__global__ void deg_kernel(const int* __restrict__ dst, float* __restrict__ deg, int nE) {
    int e = blockIdx.x * 256 + threadIdx.x;
    if (e < nE) atomicAdd(&deg[dst[e]], 1.0f);
}

// ---------------- encoder: one wave per item, precomputed S/Ov ----------------

template <bool NODE>
__global__ __launch_bounds__(512) void enc2_kernel(
    const int* __restrict__ src, const int* __restrict__ dst,
    const float* __restrict__ Sg, const float* __restrict__ Ovg,
    const float* __restrict__ OvcG, const float* __restrict__ OvsG,
    const float* __restrict__ s0x, const float* __restrict__ s2x,
    const float* __restrict__ MC8,
    const float* __restrict__ cls_w, const float* __restrict__ out_b,
    const float* __restrict__ ln1_g, const float* __restrict__ ln1_b,
    const float* __restrict__ ln2_g, const float* __restrict__ ln2_b,
    const float* __restrict__ ff1_w, const float* __restrict__ ff1_b,
    const float* __restrict__ ff2_w, const float* __restrict__ ff2_b,
    const float* __restrict__ mc_w,
    const int* __restrict__ rowbase, const int* __restrict__ estride,
    float* __restrict__ mem_out, float* __restrict__ out_cat, float* __restrict__ out_label,
    int count) {
    __shared__ f32x4 OvcS[256];   // [m][l]{h}
    __shared__ f32x4 OvsS[64];    // [l]{h}
    __shared__ f32x4 mcgS[64];    // [l]{c} = mc_w[c][l]*g2[l]
    __shared__ float clsS[256];   // [m][l]
    __shared__ float F1S[1024];   // [j][f]
    __shared__ float F2S[1024];   // [f][l]
    __shared__ f32x4 s0S[4], s2S[4], McS[1], CcS[1];
    int tid = threadIdx.x;
    for (int p = tid; p < 256; p += 512) {
        OvcS[p] = ((const f32x4*)OvcG)[p];
        clsS[p] = cls_w[p];
    }
    if (tid < 64) {
        OvsS[tid] = ((const f32x4*)OvsG)[tid];
        float g = ln2_g[tid];
        f32x4 mg = {mc_w[tid] * g, mc_w[64 + tid] * g, mc_w[128 + tid] * g, mc_w[192 + tid] * g};
        mcgS[tid] = mg;
    }
    for (int p = tid; p < 1024; p += 512) {
        int j = p >> 4, f = p & 15;
        F1S[p] = ff1_w[f * 64 + j];              // F1S[j*16+f]
        int f2 = p >> 6, l2 = p & 63;
        F2S[p] = ff2_w[l2 * 16 + f2];            // F2S[f2*64+l2]
    }
    if (tid < 4) { s0S[tid] = ((const f32x4*)s0x)[tid]; s2S[tid] = ((const f32x4*)s2x)[tid]; }
    if (tid == 0) { McS[0] = ((const f32x4*)MC8)[0]; CcS[0] = ((const f32x4*)MC8)[1]; }
    __syncthreads();

    int w = tid >> 6, l = tid & 63, h = l >> 4;
    int item = blockIdx.x * 8 + w;
    if (item >= count) return;

    int ia = NODE ? item : src[item];
    f32x4 Ova = ((const f32x4*)Ovg)[(size_t)ia * 64 + l];
    f32x4 Sa = *(const f32x4*)(Sg + (size_t)ia * 16 + h * 4);
    f32x4 Ovb, Sb;
    if (NODE) { Ovb = Ova; Sb = Sa; }
    else {
        int ib = dst[item];
        Ovb = ((const f32x4*)Ovg)[(size_t)ib * 64 + l];
        Sb = *(const f32x4*)(Sg + (size_t)ib * 16 + h * 4);
    }
    float g1 = ln1_g[l], b1 = ln1_b[l], g2v = ln2_g[l], b2v = ln2_b[l];
    float obv = out_b[l], f1bv = ff1_b[l & 15], f2bv = ff2_b[l];
    f32x4 Ovsl = OvsS[l], mg = mcgS[l];
    f32x4 s0v = s0S[h], s2v = s2S[h], Mc = McS[0], Cc = CcS[0];
    int rb = 0, st = 0;
    if (!NODE) { rb = rowbase[item]; st = estride[item]; }

    // Stage A: attention + out-proj + LN1, all 4 slots
    float x1a[4];
#pragma unroll
    for (int m = 0; m < 4; m++) {
        float s0 = s0v[m], s1 = Sa[m], s2 = s2v[m], s3 = Sb[m];
        float mx = fmaxf(fmaxf(s0, s1), fmaxf(s2, s3));
        float e0 = __expf(s0 - mx), e1 = __expf(s1 - mx), e2 = __expf(s2 - mx), e3 = __expf(s3 - mx);
        float inv = 1.f / (e0 + e1 + e2 + e3);
        float w0 = e0 * inv, w1 = e1 * inv, w2 = e2 * inv, w3 = e3 * inv;
        float x = clsS[m * 64 + l] + obv;
        f32x4 oc = OvcS[m * 64 + l];
#pragma unroll
        for (int hh = 0; hh < 4; hh++) {
            float W0 = rl(w0, hh * 16), W1 = rl(w1, hh * 16);
            float W2 = rl(w2, hh * 16), W3 = rl(w3, hh * 16);
            x += W0 * oc[hh] + W1 * Ova[hh] + W2 * Ovsl[hh] + W3 * Ovb[hh];
        }
        float sx = wsum64v(x), sxx = wsum64v(x * x);
        float mu = sx * (1.f / 64.f);
        float var = sxx * (1.f / 64.f) - mu * mu;
        float r1 = rsqrtf(var + 1e-5f);
        x1a[m] = (x - mu) * r1 * g1 + b1;
    }

    // Stage B: FF (shared weight reads across slots)
    float hp0 = 0.f, hp1 = 0.f, hp2 = 0.f, hp3 = 0.f;
    int fq = l & 15;
#pragma unroll 16
    for (int j = 0; j < 64; j++) {
        float wv = F1S[j * 16 + fq];
        hp0 += wv * rl(x1a[0], j);
        hp1 += wv * rl(x1a[1], j);
        hp2 += wv * rl(x1a[2], j);
        hp3 += wv * rl(x1a[3], j);
    }
    float hr0 = fmaxf(hp0 + f1bv, 0.f), hr1 = fmaxf(hp1 + f1bv, 0.f);
    float hr2 = fmaxf(hp2 + f1bv, 0.f), hr3 = fmaxf(hp3 + f1bv, 0.f);
    float y0 = x1a[0] + f2bv, y1 = x1a[1] + f2bv, y2 = x1a[2] + f2bv, y3 = x1a[3] + f2bv;
#pragma unroll
    for (int f2i = 0; f2i < 16; f2i++) {
        float wv = F2S[f2i * 64 + l];
        y0 += wv * rl(hr0, f2i);
        y1 += wv * rl(hr1, f2i);
        y2 += wv * rl(hr2, f2i);
        y3 += wv * rl(hr3, f2i);
    }

    // Stage C: LN2 + cat + mem, per slot
    float yv[4] = {y0, y1, y2, y3};
    float mem = 0.f;
#pragma unroll
    for (int m = 0; m < 4; m++) {
        float y = yv[m];
        float sy = wsum64v(y), syy = wsum64v(y * y);
        float mu2 = sy * (1.f / 64.f);
        float var2 = syy * (1.f / 64.f) - mu2 * mu2;
        float r2 = rsqrtf(var2 + 1e-5f);
        float t = (y - mu2) * r2 * g2v + b2v;
        mem += t;
        if (!NODE) {
            float d0 = wsum64v(mg[0] * y), d1 = wsum64v(mg[1] * y);
            float d2 = wsum64v(mg[2] * y), d3 = wsum64v(mg[3] * y);
            float c0 = r2 * (d0 - mu2 * Mc[0]) + Cc[0];
            float c1 = r2 * (d1 - mu2 * Mc[1]) + Cc[1];
            float c2 = r2 * (d2 - mu2 * Mc[2]) + Cc[2];
            float c3 = r2 * (d3 - mu2 * Mc[3]) + Cc[3];
            int row = rb + m * st;
            if (l < 4) {
                float cv = l == 0 ? c0 : (l == 1 ? c1 : (l == 2 ? c2 : c3));
                out_cat[(size_t)row * 4 + l] = cv;
            }
            if (l == 0) out_label[row] = (float)m;
        }
    }
    mem_out[(size_t)item * 64 + l] = mem;
}

// ---------------- message bilinear via MFMA (unchanged from R2) ----------------

template <bool NODE>
__global__ __launch_bounds__(256, 2) void msg_mfma(
    const float* __restrict__ feat, const int* __restrict__ src, const int* __restrict__ dstv,
    const float* __restrict__ memv, const unsigned short* __restrict__ Wstg,
    float* __restrict__ outv, int count) {
    constexpr int RS = 72;
    __shared__ __align__(16) unsigned short Wt[4 * 64 * RS];
    __shared__ float hT[4 * 256];
    int tid = threadIdx.x;
    int w = tid >> 6, lane = tid & 63;
    int m16 = lane & 15, q = lane >> 4;
    int blockbase = blockIdx.x * 256;
    int wavebase = w * 64;

    float memf[4][2][8];
#pragma unroll
    for (int Mt = 0; Mt < 4; Mt++) {
        int it = blockbase + wavebase + Mt * 16 + m16;
        if (it >= count) it = count - 1;
        const float* mrow = memv + (size_t)it * 64;
#pragma unroll
        for (int ks = 0; ks < 2; ks++) {
            float4 a = *(const float4*)(mrow + ks * 32 + q * 8);
            float4 b = *(const float4*)(mrow + ks * 32 + q * 8 + 4);
            memf[Mt][ks][0] = a.x; memf[Mt][ks][1] = a.y;
            memf[Mt][ks][2] = a.z; memf[Mt][ks][3] = a.w;
            memf[Mt][ks][4] = b.x; memf[Mt][ks][5] = b.y;
            memf[Mt][ks][6] = b.z; memf[Mt][ks][7] = b.w;
        }
    }
    f32x4 acc[4][4];
#pragma unroll
    for (int Mt = 0; Mt < 4; Mt++)
#pragma unroll
        for (int nt = 0; nt < 4; nt++) {
            f32x4 z = {0.f, 0.f, 0.f, 0.f};
            acc[Mt][nt] = z;
        }

    for (int ch = 0; ch < 16; ch++) {
        __syncthreads();
        const unsigned short* gsl = Wstg + (size_t)ch * 4 * 4096;
#pragma unroll
        for (int p = 0; p < 8; p++) {
            int flat = p * 2048 + tid * 8;
            int ic = flat >> 12, o = (flat >> 6) & 63, d = flat & 63;
            uint4 v = *(const uint4*)(gsl + flat);
            *(uint4*)&Wt[(ic * 64 + o) * RS + d] = v;
        }
        {
            int it = blockbase + tid;
            if (it >= count) it = count - 1;
            int hidx = NODE ? it : src[it];
            float4 hv = *(const float4*)(feat + (size_t)hidx * 64 + ch * 4);
            hT[0 * 256 + tid] = hv.x;
            hT[1 * 256 + tid] = hv.y;
            hT[2 * 256 + tid] = hv.z;
            hT[3 * 256 + tid] = hv.w;
        }
        __syncthreads();

#pragma unroll
        for (int il = 0; il < 4; il++) {
            float hM[4];
#pragma unroll
            for (int Mt = 0; Mt < 4; Mt++)
                hM[Mt] = hT[il * 256 + wavebase + Mt * 16 + m16];
            bf16x8 afr[4][2];
#pragma unroll
            for (int Mt = 0; Mt < 4; Mt++)
#pragma unroll
                for (int ks = 0; ks < 2; ks++) {
                    union { unsigned u[4]; bf16x8 v; } uu;
#pragma unroll
                    for (int jj = 0; jj < 4; jj++) {
                        float p0 = memf[Mt][ks][jj * 2 + 0] * hM[Mt];
                        float p1 = memf[Mt][ks][jj * 2 + 1] * hM[Mt];
                        uu.u[jj] = pack_bf2(p0, p1);
                    }
                    afr[Mt][ks] = uu.v;
                }
            const unsigned short* wrow = &Wt[(il * 64) * RS];
#pragma unroll
            for (int nt = 0; nt < 4; nt++) {
#pragma unroll
                for (int ks = 0; ks < 2; ks++) {
                    int o = nt * 16 + m16;
                    union { uint4 u; bf16x8 v; } bb;
                    bb.u = *(const uint4*)&wrow[o * RS + ks * 32 + q * 8];
#pragma unroll
                    for (int Mt = 0; Mt < 4; Mt++)
                        acc[Mt][nt] = __builtin_amdgcn_mfma_f32_16x16x32_bf16(
                            afr[Mt][ks], bb.v, acc[Mt][nt], 0, 0, 0);
                }
            }
        }
    }
#pragma unroll
    for (int Mt = 0; Mt < 4; Mt++) {
        int ib = blockbase + wavebase + Mt * 16 + q * 4;
        if (NODE) {
#pragma unroll
            for (int r = 0; r < 4; r++) {
                int it = ib + r;
                if (it < count) {
#pragma unroll
                    for (int nt = 0; nt < 4; nt++)
                        outv[(size_t)it * 64 + nt * 16 + m16] = acc[Mt][nt][r];
                }
            }
        } else {
            int4 dd = *(const int4*)(dstv + ib);
#pragma unroll
            for (int r = 0; r < 4; r++) {
                int it = ib + r;
                if (it < count) {
                    int dn = (&dd.x)[r];
#pragma unroll
                    for (int nt = 0; nt < 4; nt++)
                        atomicAdd(&outv[(size_t)dn * 64 + nt * 16 + m16], acc[Mt][nt][r]);
                }
            }
        }
    }
}

// ---------------- final node combine ----------------

__global__ __launch_bounds__(256) void final_kernel(
    const float* __restrict__ agg, const float* __restrict__ deg, const float* __restrict__ msgn,
    const float* __restrict__ lnw_g, const float* __restrict__ lnw_b,
    const float* __restrict__ h_bias, float* __restrict__ outp, int nN) {
    int tid = threadIdx.x, w = tid >> 6, l = tid & 63;
    int n = blockIdx.x * 4 + w;
    if (n >= nN) return;
    float a = agg[(size_t)n * 64 + l] / fmaxf(deg[n], 1.f);
    float mu = wsum64(a) * (1.f / 64.f);
    float d = a - mu;
    float var = wsum64(d * d) * (1.f / 64.f);
    float v = d * rsqrtf(var + 1e-5f) * lnw_g[l] + lnw_b[l] + h_bias[l] + msgn[(size_t)n * 64 + l];
    outp[(size_t)n * 64 + l] = v > 0.f ? v : 0.2f * v;
}

// ---------------- host ----------------

extern "C" void kernel_launch(void* const* d_in, const int* in_sizes, int n_in,
                              void* d_out, int out_size, void* d_ws, size_t ws_size,
                              hipStream_t stream) {
    const float* feat   = (const float*)d_in[0];
    const int*   src    = (const int*)d_in[1];
    const int*   dst    = (const int*)d_in[2];
    const int*   etype  = (const int*)d_in[3];
    const float* cls_w  = (const float*)d_in[4];
    const float* sep    = (const float*)d_in[5];
    const float* in_w   = (const float*)d_in[6];
    const float* in_b   = (const float*)d_in[7];
    const float* out_w  = (const float*)d_in[8];
    const float* out_b  = (const float*)d_in[9];
    const float* ln1_g  = (const float*)d_in[10];
    const float* ln1_b  = (const float*)d_in[11];
    const float* ln2_g  = (const float*)d_in[12];
    const float* ln2_b  = (const float*)d_in[13];
    const float* ff1_w  = (const float*)d_in[14];
    const float* ff1_b  = (const float*)d_in[15];
    const float* ff2_w  = (const float*)d_in[16];
    const float* ff2_b  = (const float*)d_in[17];
    const float* mc_w   = (const float*)d_in[18];
    const float* mc_b   = (const float*)d_in[19];
    const float* memw_w = (const float*)d_in[20];
    const float* h_bias = (const float*)d_in[21];
    const float* lnw_g  = (const float*)d_in[22];
    const float* lnw_b  = (const float*)d_in[23];

    char* ws = (char*)d_ws;
    size_t off = 0;
    auto nxt = [&](size_t bytes) -> void* {
        void* p = ws + off;
        off += (bytes + 255) & ~(size_t)255;
        return p;
    };
    unsigned short* Wstg = (unsigned short*)nxt(64 * 64 * 64 * sizeof(unsigned short));
    float* P       = (float*)nxt(1024 * sizeof(float));
    float* SWg     = (float*)nxt(1024 * sizeof(float));
    float* SB16    = (float*)nxt(16 * sizeof(float));
    float* OvcG    = (float*)nxt(1024 * sizeof(float));
    float* OvsG    = (float*)nxt(256 * sizeof(float));
    float* bOvG    = (float*)nxt(256 * sizeof(float));
    float* s0x     = (float*)nxt(16 * sizeof(float));
    float* s2x     = (float*)nxt(16 * sizeof(float));
    float* MC8     = (float*)nxt(8 * sizeof(float));
    float* WOVg    = (float*)nxt(16384 * sizeof(float));
    float* Sg      = (float*)nxt((size_t)NN * 16 * sizeof(float));
    float* Ovg     = (float*)nxt((size_t)NN * 256 * sizeof(float));
    int*   bc      = (int*)nxt(625 * 5 * sizeof(int));
    int*   boff    = (int*)nxt(625 * 5 * sizeof(int));
    int*   cs      = (int*)nxt(16 * sizeof(int));
    int*   rowbase = (int*)nxt((size_t)NE * sizeof(int));
    int*   estride = (int*)nxt((size_t)NE * sizeof(int));
    float* mem_e   = (float*)nxt((size_t)NE * 64 * sizeof(float));
    float* mem_n   = (float*)nxt((size_t)NN * 64 * sizeof(float));
    float* agg     = (float*)nxt((size_t)NN * 64 * sizeof(float));
    float* deg     = (float*)nxt((size_t)NN * sizeof(float));
    float* msg_n   = (float*)nxt((size_t)NN * 64 * sizeof(float));
    (void)ws_size; (void)in_sizes; (void)n_in; (void)out_size; (void)feat;

    float* out_node  = (float*)d_out;
    float* out_cat   = out_node + (size_t)NN * 64;
    float* out_label = out_cat + (size_t)4 * NE * 4;

    hipMemsetAsync(agg, 0, (size_t)NN * 64 * sizeof(float), stream);
    hipMemsetAsync(deg, 0, (size_t)NN * sizeof(float), stream);

    prep_w<<<1024, 256, 0, stream>>>(memw_w, Wstg);
    precomp_kernel<<<1, 64, 0, stream>>>(cls_w, sep, in_w, in_b, P);
    prep2_kernel<<<1, 256, 0, stream>>>(in_w, in_b, out_w, mc_w, mc_b, ln2_g, ln2_b, P,
                                        SWg, SB16, OvcG, OvsG, bOvG, s0x, s2x, MC8);
    prep_wov<<<64, 256, 0, stream>>>(in_w, out_w, WOVg);

    int nb = (NE + 255) / 256;  // 625
    hist_kernel<<<nb, 256, 0, stream>>>(etype, bc, NE);
    scan_kernel<<<1, 64, 0, stream>>>(bc, boff, cs, nb);
    rank_kernel<<<nb, 256, 0, stream>>>(etype, boff, cs, rowbase, estride, NE);
    deg_kernel<<<nb, 256, 0, stream>>>(dst, deg, NE);

    node_pre<<<NN / 4, 256, 0, stream>>>(feat, SWg, SB16, WOVg, bOvG, Sg, Ovg);

    enc2_kernel<false><<<(NE + 7) / 8, 512, 0, stream>>>(
        src, dst, Sg, Ovg, OvcG, OvsG, s0x, s2x, MC8, cls_w, out_b,
        ln1_g, ln1_b, ln2_g, ln2_b, ff1_w, ff1_b, ff2_w, ff2_b, mc_w,
        rowbase, estride, mem_e, out_cat, out_label, NE);
    enc2_kernel<true><<<(NN + 7) / 8, 512, 0, stream>>>(
        nullptr, nullptr, Sg, Ovg, OvcG, OvsG, s0x, s2x, MC8, cls_w, out_b,
        ln1_g, ln1_b, ln2_g, ln2_b, ff1_w, ff1_b, ff2_w, ff2_b, mc_w,
        nullptr, nullptr, mem_n, nullptr, nullptr, NN);

    msg_mfma<false><<<(NE + 255) / 256, 256, 0, stream>>>(feat, src, dst, mem_e, Wstg, agg, NE);
    msg_mfma<true><<<(NN + 255) / 256, 256, 0, stream>>>(feat, nullptr, nullptr, mem_n, Wstg, msg_n, NN);

    final_kernel<<<(NN + 3) / 4, 256, 0, stream>>>(agg, deg, msg_n, lnw_g, lnw_b, h_bias, out_node, NN);
}